// Round 3
// baseline (478.726 us; speedup 1.0000x reference)
//
#include <hip/hip_runtime.h>

// p/v trajectory double-scan, K = 2^23 fp32 3-vectors.
// Aligned-stream formulation: z_m = f[m]; E_i = excl prefix(z); H_i = sum_{m<=i} E_m.
// Then S_i = f0 + E_i, T_i = (i+1) f0 + H_i, and
//   v_i = v0 + Cc*S_i + GZ*(i+1) e3
//   p_i = p0 + DT*(i+1)*v0 + DT*Cc*T_i - DT/2*Cc*S_i + DT/2*GZ*(i+1)^2 e3
// Segment operator on (A = sum z, W = sum of seg-local excl prefix, L):
//   (A,W,L) = (A1+A2, W1 + L2*A1 + W2, L1+L2)

namespace {
constexpr int  KE    = 8388608;               // 2^23
constexpr int  CHUNK = 2048;                  // elements per scan block
constexpr int  NB    = KE / CHUNK;            // 4096
constexpr int  BLOCK = 256;
constexpr int  R     = CHUNK / BLOCK;         // 8 elements/thread (contiguous)
constexpr int  PRET  = 1024;                  // k_pre threads
constexpr int  BPT   = NB / PRET;             // 4 blocks per k_pre thread
constexpr float DTc = 0.01f;
constexpr float Cc  = 0.01f / 1.5f;           // DT/M
constexpr float GZ  = -0.01f * 9.81f;         // DT * (-G)
typedef float f32x4 __attribute__((ext_vector_type(4)));
}

// ---------- k_agg: per-block A = sum z, Bw = sum j*z  (j = in-block position) ----------
__global__ __launch_bounds__(BLOCK) void k_agg(const float* __restrict__ f,
                                               float* __restrict__ W) {
  const int b = blockIdx.x, t = threadIdx.x;
  const int lane = t & 63, wid = t >> 6;
  const float4* src = (const float4*)(f + (size_t)3 * CHUNK * b);
  float A[3] = {0.f, 0.f, 0.f}, Bw[3] = {0.f, 0.f, 0.f};
#pragma unroll
  for (int it = 0; it < 2; ++it) {
    int q3 = it * BLOCK + t;                  // triple index, elems 4q3..4q3+3
    float4 d0 = src[3 * q3], d1 = src[3 * q3 + 1], d2 = src[3 * q3 + 2];
    float j0 = (float)(4 * q3), j1 = j0 + 1.f, j2 = j0 + 2.f, j3 = j0 + 3.f;
    A[0] += d0.x; Bw[0] += j0 * d0.x;  A[1] += d0.y; Bw[1] += j0 * d0.y;  A[2] += d0.z; Bw[2] += j0 * d0.z;
    A[0] += d0.w; Bw[0] += j1 * d0.w;  A[1] += d1.x; Bw[1] += j1 * d1.x;  A[2] += d1.y; Bw[2] += j1 * d1.y;
    A[0] += d1.z; Bw[0] += j2 * d1.z;  A[1] += d1.w; Bw[1] += j2 * d1.w;  A[2] += d2.x; Bw[2] += j2 * d2.x;
    A[0] += d2.y; Bw[0] += j3 * d2.y;  A[1] += d2.z; Bw[1] += j3 * d2.z;  A[2] += d2.w; Bw[2] += j3 * d2.w;
  }
#pragma unroll
  for (int d = 32; d >= 1; d >>= 1) {
#pragma unroll
    for (int q = 0; q < 3; ++q) {
      A[q]  += __shfl_down(A[q], d);
      Bw[q] += __shfl_down(Bw[q], d);
    }
  }
  __shared__ float wag[4][6];
  if (lane == 0) {
#pragma unroll
    for (int q = 0; q < 3; ++q) { wag[wid][q] = A[q]; wag[wid][3 + q] = Bw[q]; }
  }
  __syncthreads();
  if (t == 0) {
#pragma unroll
    for (int q = 0; q < 3; ++q) {
      W[q * NB + b]       = wag[0][q] + wag[1][q] + wag[2][q] + wag[3][q];
      W[(3 + q) * NB + b] = wag[0][3 + q] + wag[1][3 + q] + wag[2][3 + q] + wag[3][3 + q];
    }
  }
}

// ---------- k_pre: cross-block exclusive (Eg, Hg) per block, fp64, 1024 threads ----------
__global__ __launch_bounds__(PRET) void k_pre(const float* __restrict__ W,
                                              float* __restrict__ W2) {
  const int t = threadIdx.x, lane = t & 63, wid = t >> 6;   // 16 waves
  double Ac[BPT][3], Wc[BPT][3];
#pragma unroll
  for (int k = 0; k < BPT; ++k) {
    const int c = BPT * t + k;
#pragma unroll
    for (int q = 0; q < 3; ++q) {
      double a  = (double)W[q * NB + c];
      double bw = (double)W[(3 + q) * NB + c];
      Ac[k][q] = a;
      Wc[k][q] = (double)(CHUNK - 1) * a - bw;   // sum (CHUNK-1-j)*z over block
    }
  }
  double tA[3] = {0, 0, 0}, tW[3] = {0, 0, 0};
#pragma unroll
  for (int k = 0; k < BPT; ++k) {
#pragma unroll
    for (int q = 0; q < 3; ++q) {
      tW[q] += (double)((BPT - 1 - k) * CHUNK) * Ac[k][q] + Wc[k][q];
      tA[q] += Ac[k][q];
    }
  }
  // Kogge-Stone over wave; receiving lane's current segment = d*BPT*CHUNK elements
#pragma unroll
  for (int d = 1; d < 64; d <<= 1) {
    double pA[3], pW[3];
#pragma unroll
    for (int q = 0; q < 3; ++q) { pA[q] = __shfl_up(tA[q], d); pW[q] = __shfl_up(tW[q], d); }
    if (lane >= d) {
      const double Ld = (double)(d * BPT * CHUNK);
#pragma unroll
      for (int q = 0; q < 3; ++q) { tW[q] = pW[q] + Ld * pA[q] + tW[q]; tA[q] += pA[q]; }
    }
  }
  double eA[3], eW[3];
#pragma unroll
  for (int q = 0; q < 3; ++q) { eA[q] = __shfl_up(tA[q], 1); eW[q] = __shfl_up(tW[q], 1); }
  if (lane == 0) {
#pragma unroll
    for (int q = 0; q < 3; ++q) { eA[q] = 0.0; eW[q] = 0.0; }
  }
  __shared__ double wag[16][6];
  if (lane == 63) {
#pragma unroll
    for (int q = 0; q < 3; ++q) { wag[wid][q] = tA[q]; wag[wid][3 + q] = tW[q]; }
  }
  __syncthreads();
  double oA[3] = {0, 0, 0}, oW[3] = {0, 0, 0};
  for (int w = 0; w < wid; ++w) {
#pragma unroll
    for (int q = 0; q < 3; ++q) oW[q] = oW[q] + (double)(64 * BPT * CHUNK) * oA[q] + wag[w][3 + q];
#pragma unroll
    for (int q = 0; q < 3; ++q) oA[q] += wag[w][q];
  }
  double Ex[3], Hx[3];
#pragma unroll
  for (int q = 0; q < 3; ++q) {
    Ex[q] = oA[q] + eA[q];
    Hx[q] = oW[q] + (double)(lane * BPT * CHUNK) * oA[q] + eW[q];
  }
#pragma unroll
  for (int k = 0; k < BPT; ++k) {
    const int c = BPT * t + k;
#pragma unroll
    for (int q = 0; q < 3; ++q) {
      W2[6 * c + q]     = (float)Ex[q];          // Eg: excl elem-sum before block c
      W2[6 * c + 3 + q] = (float)Hx[q];          // Hg: sum of E over elems before block c
      Hx[q] += (double)CHUNK * Ex[q] + Wc[k][q];
      Ex[q] += Ac[k][q];
    }
  }
}

// ---------- k_scan: register-resident scan + fused epilogue ----------
__global__ __launch_bounds__(BLOCK) void k_scan(const float* __restrict__ f,
                                                const float* __restrict__ W2,
                                                const float* __restrict__ p0v,
                                                const float* __restrict__ v0v,
                                                float* __restrict__ out) {
  const int b = blockIdx.x, t = threadIdx.x;
  const int lane = t & 63, wid = t >> 6;
  const long start = (long)b * CHUNK;
  const int j0 = t * R;

  // thread's 8 elements = 24 contiguous floats = 6 float4 loads
  float z[3 * R];
  {
    const float4* src = (const float4*)(f + 3 * start) + 6 * t;
#pragma unroll
    for (int u = 0; u < 6; ++u) {
      float4 d = src[u];
      z[4 * u] = d.x; z[4 * u + 1] = d.y; z[4 * u + 2] = d.z; z[4 * u + 3] = d.w;
    }
  }
  // per-thread aggregates: A = sum z, W = sum (R-1-e)*z
  float tS[3] = {0, 0, 0}, tT[3] = {0, 0, 0};
#pragma unroll
  for (int e = 0; e < R; ++e) {
    const float wt = (float)(R - 1 - e);
#pragma unroll
    for (int q = 0; q < 3; ++q) { float v = z[3 * e + q]; tS[q] += v; tT[q] += wt * v; }
  }
  // wave Kogge-Stone with (A,W,L) operator
#pragma unroll
  for (int d = 1; d < 64; d <<= 1) {
    float pS[3], pT[3];
#pragma unroll
    for (int q = 0; q < 3; ++q) { pS[q] = __shfl_up(tS[q], d); pT[q] = __shfl_up(tT[q], d); }
    if (lane >= d) {
      const float Ld = (float)(R * d);
#pragma unroll
      for (int q = 0; q < 3; ++q) { tT[q] = pT[q] + Ld * pS[q] + tT[q]; tS[q] += pS[q]; }
    }
  }
  float eS[3], eT[3];
#pragma unroll
  for (int q = 0; q < 3; ++q) { eS[q] = __shfl_up(tS[q], 1); eT[q] = __shfl_up(tT[q], 1); }
  if (lane == 0) {
#pragma unroll
    for (int q = 0; q < 3; ++q) { eS[q] = 0.f; eT[q] = 0.f; }
  }
  __shared__ float wag[4][6];
  if (lane == 63) {
#pragma unroll
    for (int q = 0; q < 3; ++q) { wag[wid][q] = tS[q]; wag[wid][3 + q] = tT[q]; }
  }
  __syncthreads();
  float oS[3] = {0, 0, 0}, oT[3] = {0, 0, 0};
  for (int w = 0; w < wid; ++w) {
#pragma unroll
    for (int q = 0; q < 3; ++q) oT[q] = oT[q] + 512.0f * oS[q] + wag[w][3 + q];
#pragma unroll
    for (int q = 0; q < 3; ++q) oS[q] += wag[w][q];
  }
  // absolute thread-entry (E0, H0)
  float E0[3], H0[3];
#pragma unroll
  for (int q = 0; q < 3; ++q) {
    const float Eg = W2[6 * b + q], Hg = W2[6 * b + 3 + q];
    E0[q] = Eg + oS[q] + eS[q];
    H0[q] = Hg + (float)(R * t) * Eg + (oT[q] + (float)(R * lane) * oS[q] + eT[q]);
  }
  const float f0[3] = {f[0], f[1], f[2]};
  const float p0x = p0v[0], p0y = p0v[1], p0z = p0v[2];
  const float v0x = v0v[0], v0y = v0v[1], v0z = v0v[2];
  const float a1 = DTc * Cc, a2 = 0.5f * DTc * Cc, c3 = 0.5f * DTc * GZ;

  float lsum[3] = {0, 0, 0};
  float runH[3] = {H0[0], H0[1], H0[2]};
  f32x4* pw = (f32x4*)(out + 3 * (start + j0));
  f32x4* vw = (f32x4*)(out + (size_t)3 * KE + 3 * (start + j0));
#pragma unroll
  for (int g = 0; g < 2; ++g) {
    float pe[12], ve[12];
#pragma unroll
    for (int e4 = 0; e4 < 4; ++e4) {
      const int e = 4 * g + e4;
      const float n1 = (float)(int)(start + j0 + e + 1);   // < 2^24, exact
      float S_[3], T_[3];
#pragma unroll
      for (int q = 0; q < 3; ++q) {
        const float curE = E0[q] + lsum[q];    // E_i
        runH[q] += curE;                       // H_i
        S_[q] = f0[q] + curE;
        T_[q] = n1 * f0[q] + runH[q];
        lsum[q] += z[3 * e + q];
      }
      ve[3 * e4 + 0] = v0x + Cc * S_[0];
      ve[3 * e4 + 1] = v0y + Cc * S_[1];
      ve[3 * e4 + 2] = v0z + Cc * S_[2] + GZ * n1;
      pe[3 * e4 + 0] = p0x + DTc * n1 * v0x + a1 * T_[0] - a2 * S_[0];
      pe[3 * e4 + 1] = p0y + DTc * n1 * v0y + a1 * T_[1] - a2 * S_[1];
      pe[3 * e4 + 2] = p0z + DTc * n1 * v0z + a1 * T_[2] - a2 * S_[2] + c3 * n1 * n1;
    }
#pragma unroll
    for (int u = 0; u < 3; ++u) {
      f32x4 pv = {pe[4 * u], pe[4 * u + 1], pe[4 * u + 2], pe[4 * u + 3]};
      f32x4 vv = {ve[4 * u], ve[4 * u + 1], ve[4 * u + 2], ve[4 * u + 3]};
      __builtin_nontemporal_store(pv, pw + 3 * g + u);
      __builtin_nontemporal_store(vv, vw + 3 * g + u);
    }
  }
}

extern "C" void kernel_launch(void* const* d_in, const int* in_sizes, int n_in,
                              void* d_out, int out_size, void* d_ws, size_t ws_size,
                              hipStream_t stream) {
  const float* f  = (const float*)d_in[0];
  const float* p0 = (const float*)d_in[1];
  const float* v0 = (const float*)d_in[2];
  float* out = (float*)d_out;
  float* W   = (float*)d_ws;            // 6*NB floats: A[3][NB], Bw[3][NB]
  float* W2  = W + 6 * NB;              // 6*NB floats: per-block (Eg[3], Hg[3])
  k_agg <<<NB, BLOCK, 0, stream>>>(f, W);
  k_pre <<<1, PRET, 0, stream>>>(W, W2);
  k_scan<<<NB, BLOCK, 0, stream>>>(f, W2, p0, v0, out);
}

// Round 4
// 75.648 us; speedup vs baseline: 6.3284x; 6.3284x over previous
//
#include <hip/hip_runtime.h>

// p/v trajectory double-scan, K = 2^23 fp32 3-vectors.
// Aligned-stream formulation: z_m = f[m]; E_i = excl prefix(z); H_i = sum_{m<=i} E_m.
// S_i = f0 + E_i, T_i = (i+1) f0 + H_i;
//   v_i = v0 + Cc*S_i + GZ*(i+1) e3
//   p_i = p0 + DT*(i+1)*v0 + DT*Cc*T_i - DT/2*Cc*S_i + DT/2*GZ*(i+1)^2 e3
// Segment operator on (A = sum z, W = sum of seg-local excl prefix, L):
//   (A,W,L) = (A1+A2, W1 + L2*A1 + W2, L1+L2)
// k_scan stages f and both outputs through a padded LDS transpose buffer so
// ALL global traffic is lane-consecutive float4 (round-3 lesson: 96B-stride
// nontemporal stores caused 2.6x HBM write amplification).

namespace {
constexpr int  KE    = 8388608;               // 2^23
constexpr int  CHUNK = 2048;                  // elements per scan block
constexpr int  NB    = KE / CHUNK;            // 4096
constexpr int  BLOCK = 256;
constexpr int  R     = CHUNK / BLOCK;         // 8 elements/thread (contiguous)
constexpr int  NF4   = 3 * CHUNK / 4;         // 1536 float4s per block
constexpr int  PRET  = 1024;                  // k_pre threads
constexpr int  BPT   = NB / PRET;             // 4 blocks per k_pre thread
constexpr float DTc = 0.01f;
constexpr float Cc  = 0.01f / 1.5f;           // DT/M
constexpr float GZ  = -0.01f * 9.81f;         // DT * (-G)
typedef float f32x4 __attribute__((ext_vector_type(4)));
__device__ __forceinline__ int physf4(int q) { return 7 * (q / 6) + q % 6; }
}

// ---------- k_agg: per-block A = sum z, Bw = sum j*z  (j = in-block position) ----------
__global__ __launch_bounds__(BLOCK) void k_agg(const float* __restrict__ f,
                                               float* __restrict__ W) {
  const int b = blockIdx.x, t = threadIdx.x;
  const int lane = t & 63, wid = t >> 6;
  const float4* src = (const float4*)(f + (size_t)3 * CHUNK * b);
  float A[3] = {0.f, 0.f, 0.f}, Bw[3] = {0.f, 0.f, 0.f};
#pragma unroll
  for (int it = 0; it < 2; ++it) {
    int q3 = it * BLOCK + t;                  // triple index, elems 4q3..4q3+3
    float4 d0 = src[3 * q3], d1 = src[3 * q3 + 1], d2 = src[3 * q3 + 2];
    float j0 = (float)(4 * q3), j1 = j0 + 1.f, j2 = j0 + 2.f, j3 = j0 + 3.f;
    A[0] += d0.x; Bw[0] += j0 * d0.x;  A[1] += d0.y; Bw[1] += j0 * d0.y;  A[2] += d0.z; Bw[2] += j0 * d0.z;
    A[0] += d0.w; Bw[0] += j1 * d0.w;  A[1] += d1.x; Bw[1] += j1 * d1.x;  A[2] += d1.y; Bw[2] += j1 * d1.y;
    A[0] += d1.z; Bw[0] += j2 * d1.z;  A[1] += d1.w; Bw[1] += j2 * d1.w;  A[2] += d2.x; Bw[2] += j2 * d2.x;
    A[0] += d2.y; Bw[0] += j3 * d2.y;  A[1] += d2.z; Bw[1] += j3 * d2.z;  A[2] += d2.w; Bw[2] += j3 * d2.w;
  }
#pragma unroll
  for (int d = 32; d >= 1; d >>= 1) {
#pragma unroll
    for (int q = 0; q < 3; ++q) {
      A[q]  += __shfl_down(A[q], d);
      Bw[q] += __shfl_down(Bw[q], d);
    }
  }
  __shared__ float wag[4][6];
  if (lane == 0) {
#pragma unroll
    for (int q = 0; q < 3; ++q) { wag[wid][q] = A[q]; wag[wid][3 + q] = Bw[q]; }
  }
  __syncthreads();
  if (t == 0) {
#pragma unroll
    for (int q = 0; q < 3; ++q) {
      W[q * NB + b]       = wag[0][q] + wag[1][q] + wag[2][q] + wag[3][q];
      W[(3 + q) * NB + b] = wag[0][3 + q] + wag[1][3 + q] + wag[2][3 + q] + wag[3][3 + q];
    }
  }
}

// ---------- k_pre: cross-block exclusive (Eg, Hg) per block, fp64, 1024 threads ----------
__global__ __launch_bounds__(PRET) void k_pre(const float* __restrict__ W,
                                              float* __restrict__ W2) {
  const int t = threadIdx.x, lane = t & 63, wid = t >> 6;   // 16 waves
  double Ac[BPT][3], Wc[BPT][3];
#pragma unroll
  for (int k = 0; k < BPT; ++k) {
    const int c = BPT * t + k;
#pragma unroll
    for (int q = 0; q < 3; ++q) {
      double a  = (double)W[q * NB + c];
      double bw = (double)W[(3 + q) * NB + c];
      Ac[k][q] = a;
      Wc[k][q] = (double)(CHUNK - 1) * a - bw;   // sum (CHUNK-1-j)*z over block
    }
  }
  double tA[3] = {0, 0, 0}, tW[3] = {0, 0, 0};
#pragma unroll
  for (int k = 0; k < BPT; ++k) {
#pragma unroll
    for (int q = 0; q < 3; ++q) {
      tW[q] += (double)((BPT - 1 - k) * CHUNK) * Ac[k][q] + Wc[k][q];
      tA[q] += Ac[k][q];
    }
  }
#pragma unroll
  for (int d = 1; d < 64; d <<= 1) {
    double pA[3], pW[3];
#pragma unroll
    for (int q = 0; q < 3; ++q) { pA[q] = __shfl_up(tA[q], d); pW[q] = __shfl_up(tW[q], d); }
    if (lane >= d) {
      const double Ld = (double)(d * BPT * CHUNK);
#pragma unroll
      for (int q = 0; q < 3; ++q) { tW[q] = pW[q] + Ld * pA[q] + tW[q]; tA[q] += pA[q]; }
    }
  }
  double eA[3], eW[3];
#pragma unroll
  for (int q = 0; q < 3; ++q) { eA[q] = __shfl_up(tA[q], 1); eW[q] = __shfl_up(tW[q], 1); }
  if (lane == 0) {
#pragma unroll
    for (int q = 0; q < 3; ++q) { eA[q] = 0.0; eW[q] = 0.0; }
  }
  __shared__ double wagd[16][6];
  if (lane == 63) {
#pragma unroll
    for (int q = 0; q < 3; ++q) { wagd[wid][q] = tA[q]; wagd[wid][3 + q] = tW[q]; }
  }
  __syncthreads();
  double oA[3] = {0, 0, 0}, oW[3] = {0, 0, 0};
  for (int w = 0; w < wid; ++w) {
#pragma unroll
    for (int q = 0; q < 3; ++q) oW[q] = oW[q] + (double)(64 * BPT * CHUNK) * oA[q] + wagd[w][3 + q];
#pragma unroll
    for (int q = 0; q < 3; ++q) oA[q] += wagd[w][q];
  }
  double Ex[3], Hx[3];
#pragma unroll
  for (int q = 0; q < 3; ++q) {
    Ex[q] = oA[q] + eA[q];
    Hx[q] = oW[q] + (double)(lane * BPT * CHUNK) * oA[q] + eW[q];
  }
#pragma unroll
  for (int k = 0; k < BPT; ++k) {
    const int c = BPT * t + k;
#pragma unroll
    for (int q = 0; q < 3; ++q) {
      W2[6 * c + q]     = (float)Ex[q];          // Eg: excl elem-sum before block c
      W2[6 * c + 3 + q] = (float)Hx[q];          // Hg: sum of E over elems before block c
      Hx[q] += (double)CHUNK * Ex[q] + Wc[k][q];
      Ex[q] += Ac[k][q];
    }
  }
}

// ---------- k_scan: LDS-transposed coalesced IO + register scan + fused epilogue ----------
__global__ __launch_bounds__(BLOCK, 5) void k_scan(const float* __restrict__ f,
                                                   const float* __restrict__ W2,
                                                   const float* __restrict__ p0v,
                                                   const float* __restrict__ v0v,
                                                   float* __restrict__ out) {
  const int b = blockIdx.x, t = threadIdx.x;
  const int lane = t & 63, wid = t >> 6;
  const long start = (long)b * CHUNK;

  __shared__ f32x4 buf[7 * BLOCK];    // 28672 B padded transpose buffer
  __shared__ float wag[4][6];

  // ---- 1. coalesced global load -> LDS (blocked-padded layout)
  {
    const f32x4* src = (const f32x4*)(f + 3 * start);
#pragma unroll
    for (int it = 0; it < 6; ++it) {
      const int q = t + BLOCK * it;
      buf[physf4(q)] = src[q];
    }
  }
  __syncthreads();

  // ---- 2. thread's 8 elements = 6 float4 LDS reads at stride-7 base
  float z[3 * R];
#pragma unroll
  for (int u = 0; u < 6; ++u) {
    f32x4 d = buf[7 * t + u];
    z[4 * u] = d.x; z[4 * u + 1] = d.y; z[4 * u + 2] = d.z; z[4 * u + 3] = d.w;
  }

  // per-thread aggregates: A = sum z, W = sum (R-1-e)*z
  float tS[3] = {0, 0, 0}, tT[3] = {0, 0, 0};
#pragma unroll
  for (int e = 0; e < R; ++e) {
    const float wt = (float)(R - 1 - e);
#pragma unroll
    for (int q = 0; q < 3; ++q) { float v = z[3 * e + q]; tS[q] += v; tT[q] += wt * v; }
  }
  // wave Kogge-Stone with (A,W,L) operator
#pragma unroll
  for (int d = 1; d < 64; d <<= 1) {
    float pS[3], pT[3];
#pragma unroll
    for (int q = 0; q < 3; ++q) { pS[q] = __shfl_up(tS[q], d); pT[q] = __shfl_up(tT[q], d); }
    if (lane >= d) {
      const float Ld = (float)(R * d);
#pragma unroll
      for (int q = 0; q < 3; ++q) { tT[q] = pT[q] + Ld * pS[q] + tT[q]; tS[q] += pS[q]; }
    }
  }
  float eS[3], eT[3];
#pragma unroll
  for (int q = 0; q < 3; ++q) { eS[q] = __shfl_up(tS[q], 1); eT[q] = __shfl_up(tT[q], 1); }
  if (lane == 0) {
#pragma unroll
    for (int q = 0; q < 3; ++q) { eS[q] = 0.f; eT[q] = 0.f; }
  }
  if (lane == 63) {
#pragma unroll
    for (int q = 0; q < 3; ++q) { wag[wid][q] = tS[q]; wag[wid][3 + q] = tT[q]; }
  }
  __syncthreads();   // also: all z reads from buf are complete after this point
  float oS[3] = {0, 0, 0}, oT[3] = {0, 0, 0};
  for (int w = 0; w < wid; ++w) {
#pragma unroll
    for (int q = 0; q < 3; ++q) oT[q] = oT[q] + 512.0f * oS[q] + wag[w][3 + q];
#pragma unroll
    for (int q = 0; q < 3; ++q) oS[q] += wag[w][q];
  }
  // absolute thread-entry (E0, H0)
  float E0[3], H0[3];
#pragma unroll
  for (int q = 0; q < 3; ++q) {
    const float Eg = W2[6 * b + q], Hg = W2[6 * b + 3 + q];
    E0[q] = Eg + oS[q] + eS[q];
    H0[q] = Hg + (float)(R * t) * Eg + (oT[q] + (float)(R * lane) * oS[q] + eT[q]);
  }

  // ---- 3. fused epilogue: p -> LDS (buf reusable), v -> registers
  const float f0[3] = {f[0], f[1], f[2]};
  const float p0x = p0v[0], p0y = p0v[1], p0z = p0v[2];
  const float v0x = v0v[0], v0y = v0v[1], v0z = v0v[2];
  const float a1 = DTc * Cc, a2 = 0.5f * DTc * Cc, c3 = 0.5f * DTc * GZ;

  float lsum[3] = {0, 0, 0};
  float runH[3] = {H0[0], H0[1], H0[2]};
  float ve[3 * R];
#pragma unroll
  for (int g = 0; g < 2; ++g) {
    float pe[12];
#pragma unroll
    for (int e4 = 0; e4 < 4; ++e4) {
      const int e = 4 * g + e4;
      const float n1 = (float)(int)(start + t * R + e + 1);   // < 2^24, exact
      float S_[3], T_[3];
#pragma unroll
      for (int q = 0; q < 3; ++q) {
        const float curE = E0[q] + lsum[q];    // E_i
        runH[q] += curE;                       // H_i
        S_[q] = f0[q] + curE;
        T_[q] = n1 * f0[q] + runH[q];
        lsum[q] += z[3 * e + q];
      }
      ve[3 * e + 0] = v0x + Cc * S_[0];
      ve[3 * e + 1] = v0y + Cc * S_[1];
      ve[3 * e + 2] = v0z + Cc * S_[2] + GZ * n1;
      pe[3 * e4 + 0] = p0x + DTc * n1 * v0x + a1 * T_[0] - a2 * S_[0];
      pe[3 * e4 + 1] = p0y + DTc * n1 * v0y + a1 * T_[1] - a2 * S_[1];
      pe[3 * e4 + 2] = p0z + DTc * n1 * v0z + a1 * T_[2] - a2 * S_[2] + c3 * n1 * n1;
    }
#pragma unroll
    for (int u = 0; u < 3; ++u) {
      f32x4 pv = {pe[4 * u], pe[4 * u + 1], pe[4 * u + 2], pe[4 * u + 3]};
      buf[7 * t + 3 * g + u] = pv;
    }
  }
  __syncthreads();

  // ---- 4. coalesced nontemporal store of p
  {
    f32x4* dst = (f32x4*)out + (size_t)NF4 * b;
#pragma unroll
    for (int it = 0; it < 6; ++it) {
      const int q = t + BLOCK * it;
      f32x4 d = buf[physf4(q)];
      __builtin_nontemporal_store(d, dst + q);
    }
  }
  __syncthreads();

  // ---- 5. v through the same buffer
#pragma unroll
  for (int u = 0; u < 6; ++u) {
    f32x4 vv = {ve[4 * u], ve[4 * u + 1], ve[4 * u + 2], ve[4 * u + 3]};
    buf[7 * t + u] = vv;
  }
  __syncthreads();
  {
    f32x4* dst = (f32x4*)(out + (size_t)3 * KE) + (size_t)NF4 * b;
#pragma unroll
    for (int it = 0; it < 6; ++it) {
      const int q = t + BLOCK * it;
      f32x4 d = buf[physf4(q)];
      __builtin_nontemporal_store(d, dst + q);
    }
  }
}

extern "C" void kernel_launch(void* const* d_in, const int* in_sizes, int n_in,
                              void* d_out, int out_size, void* d_ws, size_t ws_size,
                              hipStream_t stream) {
  const float* f  = (const float*)d_in[0];
  const float* p0 = (const float*)d_in[1];
  const float* v0 = (const float*)d_in[2];
  float* out = (float*)d_out;
  float* W   = (float*)d_ws;            // 6*NB floats: A[3][NB], Bw[3][NB]
  float* W2  = W + 6 * NB;              // 6*NB floats: per-block (Eg[3], Hg[3])
  k_agg <<<NB, BLOCK, 0, stream>>>(f, W);
  k_pre <<<1, PRET, 0, stream>>>(W, W2);
  k_scan<<<NB, BLOCK, 0, stream>>>(f, W2, p0, v0, out);
}